// Round 8
// baseline (300.803 us; speedup 1.0000x reference)
//
#include <hip/hip_runtime.h>
#include <math.h>

#define BB 16
#define SS 256
#define FF 512
#define EE 128
#define HH 64
#define GG 192  // 3H
#define LL 8

__device__ __forceinline__ float sigmoid_f(float x) {
    return 1.0f / (1.0f + __expf(-x));
}
__device__ __forceinline__ float tanh_f(float x) {
    // 1 - 2/(1+e^{2x}): saturates cleanly to ±1, no NaN for large |x|
    return 1.0f - 2.0f / (1.0f + __expf(2.0f * x));
}

// ---------------------------------------------------------------------------
// Generic C[m,n] = sum_k A[m,k] * Bm[n,k] + bias[n]
// Tile: 32 rows x 64 cols, K chunks of 64. Block = 256 threads.
// ---------------------------------------------------------------------------
__device__ __forceinline__ void gemm_bt_body(
    const float* __restrict__ A, const float* __restrict__ Bm,
    const float* __restrict__ bias, float* __restrict__ C,
    int N, int K)
{
    __shared__ float As[32][68];
    __shared__ float Bs[64][68];
    const int t = threadIdx.x;
    const int row0 = blockIdx.x * 32;
    const int col0 = blockIdx.y * 64;
    const int tr = t & 7;        // 0..7 row-group
    const int tc = t >> 3;       // 0..31 col-group
    float acc[4][2] = {{0.f,0.f},{0.f,0.f},{0.f,0.f},{0.f,0.f}};

    for (int k0 = 0; k0 < K; k0 += 64) {
        {
            int r = t >> 3;          // 0..31
            int q = t & 7;           // 0..7
            const float* src = &A[(size_t)(row0 + r) * K + k0];
            #pragma unroll
            for (int it = 0; it < 2; ++it) {
                int kk = (q + it * 8) * 4;
                *(float4*)&As[r][kk] = *(const float4*)&src[kk];
            }
        }
        {
            int r = t >> 2;          // 0..63
            int q = t & 3;           // 0..3
            int n = col0 + r;
            #pragma unroll
            for (int it = 0; it < 4; ++it) {
                int kk = (q + it * 4) * 4;
                float4 v = {0.f, 0.f, 0.f, 0.f};
                if (n < N) v = *(const float4*)&Bm[(size_t)n * K + k0 + kk];
                *(float4*)&Bs[r][kk] = v;
            }
        }
        __syncthreads();
        #pragma unroll
        for (int k = 0; k < 64; k += 4) {
            float4 av[4], bv[2];
            #pragma unroll
            for (int i = 0; i < 4; ++i) av[i] = *(const float4*)&As[tr + 8*i][k];
            #pragma unroll
            for (int j = 0; j < 2; ++j) bv[j] = *(const float4*)&Bs[tc + 32*j][k];
            #pragma unroll
            for (int i = 0; i < 4; ++i)
                #pragma unroll
                for (int j = 0; j < 2; ++j)
                    acc[i][j] += av[i].x*bv[j].x + av[i].y*bv[j].y
                               + av[i].z*bv[j].z + av[i].w*bv[j].w;
        }
        __syncthreads();
    }

    #pragma unroll
    for (int i = 0; i < 4; ++i) {
        int r = row0 + tr + 8*i;
        #pragma unroll
        for (int j = 0; j < 2; ++j) {
            int c = col0 + tc + 32*j;
            if (c < N) C[(size_t)r * N + c] = acc[i][j] + bias[c];
        }
    }
}

__global__ __launch_bounds__(256) void gemm_bt(
    const float* __restrict__ A, const float* __restrict__ Bm,
    const float* __restrict__ bias, float* __restrict__ C,
    int N, int K)
{
    gemm_bt_body(A, Bm, bias, C, N, K);
}

// Two GEMMs sharing A, selected by blockIdx.z (saves a launch).
__global__ __launch_bounds__(256) void gemm_bt_dual(
    const float* __restrict__ A,
    const float* __restrict__ B0, const float* __restrict__ bias0, float* __restrict__ C0,
    const float* __restrict__ B1, const float* __restrict__ bias1, float* __restrict__ C1,
    int N, int K)
{
    const float* Bm   = blockIdx.z ? B1    : B0;
    const float* bias = blockIdx.z ? bias1 : bias0;
    float*       C    = blockIdx.z ? C1    : C0;
    gemm_bt_body(A, Bm, bias, C, N, K);
}

// ---------------------------------------------------------------------------
// GRU scan, r8: SIX waves per chain (gate x k-half), 32 blocks x 384 thr.
// Lane (g,h,j) holds Whh[g*64+j][h*32 .. h*32+32) = 8 float4 -> ~57 VGPR
// total pressure, below even the 64-VGPR max-occupancy budget, so the
// allocator CANNOT spill the weights (r2-r7: 90-220 VGPR demand was always
// spilled/remat'd regardless of attributes; ~600 stall cyc/step).
// Per step per wave: 32 readlane + 32 FMA -> partial to LDS; one lgkm-only
// barrier; ALL waves redundantly compute gates from the 6 partials and
// update h in-register (identical fp ops -> identical h in every lane, so
// readlane stays legal and no second barrier / h round-trip is needed).
// Bias + x_r/x_z folded into the half-0 partial; x_n stays outside (GRU:
// n = tanh(xn + r*(Wn h + bn))). Double-buffered partials make one
// barrier/step race-free; global loads/stores never block on the barrier.
// ---------------------------------------------------------------------------
__global__ __launch_bounds__(384)
void gru_kernel(
    const float* __restrict__ xpa, const float* __restrict__ xpb,
    const float* __restrict__ Whh_a, const float* __restrict__ bhh_a,
    const float* __restrict__ Whh_b, const float* __restrict__ bhh_b,
    float* __restrict__ hs_a, float* __restrict__ hs_b)
{
    const int blk = blockIdx.x;      // 0..31
    const int b = blk >> 1;
    const int which = blk & 1;
    const float* xp  = which ? xpb   : xpa;
    const float* Whh = which ? Whh_b : Whh_a;
    const float* bhh = which ? bhh_b : bhh_a;
    float* hs        = which ? hs_b  : hs_a;

    const int t = threadIdx.x;       // 0..383
    const int w = t >> 6;            // wave 0..5
    const int g = w >> 1;            // gate: 0=r, 1=z, 2=n
    const int hf = w & 1;            // k-half: 0 -> k<32, 1 -> k>=32
    const int j = t & 63;

    __shared__ float p_s[2][6][64];  // [buf][wave][unit] partial dots

    // 32 weights of row g*64+j, k-half hf (8 float4, ~32 VGPR).
    float4 wv[8];
    {
        const float4* wrow = (const float4*)&Whh[(size_t)(g * 64 + j) * HH + hf * 32];
        #pragma unroll
        for (int k = 0; k < 8; ++k) {
            wv[k] = wrow[k];
            asm volatile("" : "+v"(wv[k].x), "+v"(wv[k].y), "+v"(wv[k].z), "+v"(wv[k].w));
        }
    }
    // bias carried by half 0 only (added exactly once per gate)
    const float bh = (hf == 0) ? bhh[g * 64 + j] : 0.f;

    const float* xrow = xp + (size_t)b * SS * GG;
    float* hrow = hs + (size_t)b * SS * HH;
    float hcur = 0.f;

    // prefetch step 0
    float xg = xrow[g * 64 + j];     // own-gate x (folded by g<2, hf==0)
    float xn = xrow[128 + j];        // needed by all lanes for the n-gate

#define RL(v, k) __int_as_float(__builtin_amdgcn_readlane(__float_as_int(v), (k)))

    for (int s = 0; s < SS; ++s) {
        // Prefetch next step's xp (last iter reads past this xp array into
        // the adjacent workspace region — harmless, value discarded). These
        // loads stay in flight across the lgkm-only barrier.
        const float* nx = xrow + GG;
        float nxg = nx[g * 64 + j];
        float nxn = nx[128 + j];

        // half-dot: bh + W[row][hf*32 .. +32) . h[hf*32 .. +32)
        float a0 = bh, a1 = 0.f, a2 = 0.f, a3 = 0.f;
        #pragma unroll
        for (int k = 0; k < 8; ++k) {
            float4 wk = wv[k];
            const int kb = hf * 32 + 4 * k;
            a0 = fmaf(wk.x, RL(hcur, kb + 0), a0);
            a1 = fmaf(wk.y, RL(hcur, kb + 1), a1);
            a2 = fmaf(wk.z, RL(hcur, kb + 2), a2);
            a3 = fmaf(wk.w, RL(hcur, kb + 3), a3);
        }
        float part = (a0 + a1) + (a2 + a3);
        if (g < 2 && hf == 0) part += xg;   // fold x into r,z pre-activations
        p_s[s & 1][w][j] = part;

        // LDS-only barrier: wait ds_write visibility, don't drain vmcnt.
        asm volatile("s_waitcnt lgkmcnt(0)" ::: "memory");
        __builtin_amdgcn_s_barrier();
        asm volatile("" ::: "memory");

        // all waves redundantly finish the gates (keeps h in every lane)
        float pr = p_s[s & 1][0][j] + p_s[s & 1][1][j];
        float pz = p_s[s & 1][2][j] + p_s[s & 1][3][j];
        float pn = p_s[s & 1][4][j] + p_s[s & 1][5][j];
        float r = sigmoid_f(pr);
        float z = sigmoid_f(pz);
        float n = tanh_f(xn + r * pn);
        hcur = fmaf(z, hcur - n, n);   // (1-z)*n + z*h
        if (w == 0) hrow[j] = hcur;

        xg = nxg; xn = nxn;
        xrow += GG;
        hrow += HH;
    }
#undef RL
}

// ---------------------------------------------------------------------------
// Per (b,j): wj = exp(h_alpha . Wa + ba) * M;  val[e] = tanh(h_beta . Wb[e] + bb[e]) * emb[e] * wj
// Grid: B*S blocks x 128 threads (thread = e).
// ---------------------------------------------------------------------------
__global__ __launch_bounds__(128) void attn_val_kernel(
    const float* __restrict__ h_alpha, const float* __restrict__ h_beta,
    const float* __restrict__ emb, const float* __restrict__ M,
    const float* __restrict__ Wa, const float* __restrict__ ba,
    const float* __restrict__ Wb, const float* __restrict__ bb,
    float* __restrict__ val, float* __restrict__ wj)
{
    const int bj = blockIdx.x;       // 0..B*S-1
    const int t = threadIdx.x;       // 0..127
    __shared__ float hb_s[HH];
    __shared__ float wj_s;

    if (t < 64) {
        hb_s[t] = h_beta[(size_t)bj * HH + t];
        float p = h_alpha[(size_t)bj * HH + t] * Wa[t];
        #pragma unroll
        for (int off = 32; off > 0; off >>= 1) p += __shfl_down(p, off);
        if (t == 0) {
            float a = __expf(p + ba[0]) * M[bj];
            wj_s = a;
            wj[bj] = a;
        }
    }
    __syncthreads();

    float acc = bb[t];
    const float4* wrow = (const float4*)&Wb[(size_t)t * HH];
    #pragma unroll
    for (int k = 0; k < 16; ++k) {
        float4 w4 = wrow[k];
        float4 h4 = *(const float4*)&hb_s[k * 4];
        acc += w4.x*h4.x + w4.y*h4.y + w4.z*h4.z + w4.w*h4.w;
    }
    float bw = tanh_f(acc);
    val[(size_t)bj * EE + t] = bw * emb[(size_t)bj * EE + t] * wj_s;
}

// ---------------------------------------------------------------------------
// Suffix scan over j: weighted[b,i,e] = (sum_{j>=i} val[b,j,e]) / (sum_{j>=i} wj[b,j] + 1e-10)
// Grid: B blocks x 128 threads (thread = e).
// ---------------------------------------------------------------------------
__global__ __launch_bounds__(128) void scan_kernel(
    const float* __restrict__ val, const float* __restrict__ wj,
    float* __restrict__ wtd)
{
    const int b = blockIdx.x;
    const int t = threadIdx.x;   // e
    float se = 0.f;
    float d = 1e-10f;
    for (int j = SS - 1; j >= 0; --j) {
        size_t idx = ((size_t)(b * SS + j)) * EE + t;
        se += val[idx];
        d += wj[b * SS + j];
        wtd[idx] = se / d;
    }
}

// ---------------------------------------------------------------------------
// all_output[b,s,l] = (weighted[b,s,:] . Wp[l,:] + bp[l]) * M[b,s]
// Block: 32 rows x 8 l = 256 threads. Grid: 4096/32 = 128 blocks.
// ---------------------------------------------------------------------------
__global__ __launch_bounds__(256) void proj_kernel(
    const float* __restrict__ wtd, const float* __restrict__ Wp,
    const float* __restrict__ bp, const float* __restrict__ M,
    float* __restrict__ out)
{
    __shared__ float wt_s[32][132];
    __shared__ float wp_s[8][132];
    const int t = threadIdx.x;
    const int row0 = blockIdx.x * 32;

    {   // stage weighted tile: 32 x 128
        int r = t >> 3;          // 0..31
        int q = t & 7;           // 0..7
        const float* src = &wtd[(size_t)(row0 + r) * EE];
        #pragma unroll
        for (int it = 0; it < 4; ++it) {
            int kk = (q + it * 8) * 4;
            *(float4*)&wt_s[r][kk] = *(const float4*)&src[kk];
        }
    }
    {   // stage Wp: 8 x 128
        int r = t >> 5;          // 0..7
        int q = t & 31;          // 0..31
        *(float4*)&wp_s[r][q * 4] = *(const float4*)&Wp[(size_t)r * EE + q * 4];
    }
    __syncthreads();

    const int r = t >> 3, l = t & 7;
    float acc = 0.f;
    #pragma unroll
    for (int i = 0; i < 32; ++i) {
        float4 a = *(const float4*)&wt_s[r][i * 4];
        float4 w = *(const float4*)&wp_s[l][i * 4];
        acc += a.x*w.x + a.y*w.y + a.z*w.z + a.w*w.w;
    }
    const int row = row0 + r;
    out[(size_t)row * LL + l] = (acc + bp[l]) * M[row];
}

// ---------------------------------------------------------------------------
// cur_output[b,l] = sum_s all_output[b,s,l] * cur_M[b,s]
// Grid: B blocks x 256 threads.
// ---------------------------------------------------------------------------
__global__ __launch_bounds__(256) void cur_kernel(
    const float* __restrict__ out_all, const float* __restrict__ curM,
    float* __restrict__ out_cur)
{
    const int b = blockIdx.x;
    const int t = threadIdx.x;
    const int l = t & 7, c = t >> 3;   // c: 0..31
    float p = 0.f;
    #pragma unroll
    for (int k = 0; k < 8; ++k) {
        int s = c + k * 32;
        p += out_all[((size_t)(b * SS + s)) * LL + l] * curM[b * SS + s];
    }
    __shared__ float red[32][9];
    red[c][l] = p;
    __syncthreads();
    if (t < 8) {
        float sum = 0.f;
        for (int c2 = 0; c2 < 32; ++c2) sum += red[c2][t];
        out_cur[b * LL + t] = sum;
    }
}

// ---------------------------------------------------------------------------
extern "C" void kernel_launch(void* const* d_in, const int* in_sizes, int n_in,
                              void* d_out, int out_size, void* d_ws, size_t ws_size,
                              hipStream_t stream)
{
    const float* X       = (const float*)d_in[0];
    const float* M       = (const float*)d_in[1];
    const float* cur_M   = (const float*)d_in[2];
    const float* W_embed = (const float*)d_in[3];
    const float* b_embed = (const float*)d_in[4];
    const float* Wih_a   = (const float*)d_in[5];
    const float* Whh_a   = (const float*)d_in[6];
    const float* bih_a   = (const float*)d_in[7];
    const float* bhh_a   = (const float*)d_in[8];
    const float* Wih_b   = (const float*)d_in[9];
    const float* Whh_b   = (const float*)d_in[10];
    const float* bih_b   = (const float*)d_in[11];
    const float* bhh_b   = (const float*)d_in[12];
    const float* Wb      = (const float*)d_in[13];
    const float* bb      = (const float*)d_in[14];
    const float* Wa      = (const float*)d_in[15];
    const float* ba      = (const float*)d_in[16];
    const float* Wp      = (const float*)d_in[17];
    const float* bp      = (const float*)d_in[18];
    float* out = (float*)d_out;

    float* ws  = (float*)d_ws;
    float* emb = ws;                          // B*S*E   = 524288
    float* xpa = emb + (size_t)BB*SS*EE;      // B*S*192 = 786432
    float* xpb = xpa + (size_t)BB*SS*GG;
    float* ha  = xpb + (size_t)BB*SS*GG;      // B*S*H
    float* hb  = ha  + (size_t)BB*SS*HH;
    float* val = hb  + (size_t)BB*SS*HH;      // B*S*E
    float* wjv = val + (size_t)BB*SS*EE;      // B*S
    float* wtd = wjv + (size_t)BB*SS;         // B*S*E

    const int ROWS = BB * SS;                 // 4096

    // 1) emb = X @ W_embed^T + b_embed
    gemm_bt<<<dim3(ROWS/32, EE/64), 256, 0, stream>>>(X, W_embed, b_embed, emb, EE, FF);
    // 2) xp_a / xp_b = emb @ Wih^T + bih  (one dual launch, z selects GRU)
    gemm_bt_dual<<<dim3(ROWS/32, (GG+63)/64, 2), 256, 0, stream>>>(
        emb, Wih_a, bih_a, xpa, Wih_b, bih_b, xpb, GG, EE);
    // 3) both GRU scans (32 chains, 6 waves each — gate x k-half)
    gru_kernel<<<32, 384, 0, stream>>>(xpa, xpb, Whh_a, bhh_a, Whh_b, bhh_b, ha, hb);
    // 4) attention weights + per-j values
    attn_val_kernel<<<ROWS, 128, 0, stream>>>(ha, hb, emb, M, Wa, ba, Wb, bb, val, wjv);
    // 5) suffix scan -> weighted
    scan_kernel<<<BB, 128, 0, stream>>>(val, wjv, wtd);
    // 6) projection -> all_output
    proj_kernel<<<ROWS/32, 256, 0, stream>>>(wtd, Wp, bp, M, out);
    // 7) cur_output
    cur_kernel<<<BB, 256, 0, stream>>>(out, cur_M, out + (size_t)BB*SS*LL);
}

// Round 9
// 188.614 us; speedup vs baseline: 1.5948x; 1.5948x over previous
//
#include <hip/hip_runtime.h>
#include <math.h>

#define BB 16
#define SS 256
#define FF 512
#define EE 128
#define HH 64
#define GG 192  // 3H
#define LL 8
#define TT 16   // scan tile count (SS/16)

__device__ __forceinline__ float sigmoid_f(float x) {
    return 1.0f / (1.0f + __expf(-x));
}
__device__ __forceinline__ float tanh_f(float x) {
    return 1.0f - 2.0f / (1.0f + __expf(2.0f * x));
}

// ---------------------------------------------------------------------------
// Generic C[m,n] = sum_k A[m,k] * Bm[n,k] + bias[n]
// ---------------------------------------------------------------------------
__device__ __forceinline__ void gemm_bt_body(
    const float* __restrict__ A, const float* __restrict__ Bm,
    const float* __restrict__ bias, float* __restrict__ C,
    int N, int K)
{
    __shared__ float As[32][68];
    __shared__ float Bs[64][68];
    const int t = threadIdx.x;
    const int row0 = blockIdx.x * 32;
    const int col0 = blockIdx.y * 64;
    const int tr = t & 7;
    const int tc = t >> 3;
    float acc[4][2] = {{0.f,0.f},{0.f,0.f},{0.f,0.f},{0.f,0.f}};

    for (int k0 = 0; k0 < K; k0 += 64) {
        {
            int r = t >> 3;
            int q = t & 7;
            const float* src = &A[(size_t)(row0 + r) * K + k0];
            #pragma unroll
            for (int it = 0; it < 2; ++it) {
                int kk = (q + it * 8) * 4;
                *(float4*)&As[r][kk] = *(const float4*)&src[kk];
            }
        }
        {
            int r = t >> 2;
            int q = t & 3;
            int n = col0 + r;
            #pragma unroll
            for (int it = 0; it < 4; ++it) {
                int kk = (q + it * 4) * 4;
                float4 v = {0.f, 0.f, 0.f, 0.f};
                if (n < N) v = *(const float4*)&Bm[(size_t)n * K + k0 + kk];
                *(float4*)&Bs[r][kk] = v;
            }
        }
        __syncthreads();
        #pragma unroll
        for (int k = 0; k < 64; k += 4) {
            float4 av[4], bv[2];
            #pragma unroll
            for (int i = 0; i < 4; ++i) av[i] = *(const float4*)&As[tr + 8*i][k];
            #pragma unroll
            for (int j = 0; j < 2; ++j) bv[j] = *(const float4*)&Bs[tc + 32*j][k];
            #pragma unroll
            for (int i = 0; i < 4; ++i)
                #pragma unroll
                for (int j = 0; j < 2; ++j)
                    acc[i][j] += av[i].x*bv[j].x + av[i].y*bv[j].y
                               + av[i].z*bv[j].z + av[i].w*bv[j].w;
        }
        __syncthreads();
    }

    #pragma unroll
    for (int i = 0; i < 4; ++i) {
        int r = row0 + tr + 8*i;
        #pragma unroll
        for (int j = 0; j < 2; ++j) {
            int c = col0 + tc + 32*j;
            if (c < N) C[(size_t)r * N + c] = acc[i][j] + bias[c];
        }
    }
}

__global__ __launch_bounds__(256) void gemm_bt(
    const float* __restrict__ A, const float* __restrict__ Bm,
    const float* __restrict__ bias, float* __restrict__ C,
    int N, int K)
{
    gemm_bt_body(A, Bm, bias, C, N, K);
}

__global__ __launch_bounds__(256) void gemm_bt_dual(
    const float* __restrict__ A,
    const float* __restrict__ B0, const float* __restrict__ bias0, float* __restrict__ C0,
    const float* __restrict__ B1, const float* __restrict__ bias1, float* __restrict__ C1,
    int N, int K)
{
    const float* Bm   = blockIdx.z ? B1    : B0;
    const float* bias = blockIdx.z ? bias1 : bias0;
    float*       C    = blockIdx.z ? C1    : C0;
    gemm_bt_body(A, Bm, bias, C, N, K);
}

// ---------------------------------------------------------------------------
// GRU scan (r9 = r7 structure, best known @116us: 3 waves/chain, one gate per
// wave, lgkm-only barrier, double-buffered gh). Single change: weights loaded
// through a VOLATILE pointer — volatile loads cannot be rematerialized, so if
// r5-r8's "weights reloaded every step at VGPR_Count=44" was load-remat, this
// forces true residency (~90 VGPR). r8 proved multi-wave split (6 waves) is
// counterproductive: barrier/wakeup cost grows faster than per-wave work
// shrinks (1088 -> 2000 cyc/step).
// ---------------------------------------------------------------------------
__global__ __launch_bounds__(192, 1)
__attribute__((amdgpu_waves_per_eu(1, 1)))
void gru_kernel(
    const float* __restrict__ xpa, const float* __restrict__ xpb,
    const float* __restrict__ Whh_a, const float* __restrict__ bhh_a,
    const float* __restrict__ Whh_b, const float* __restrict__ bhh_b,
    float* __restrict__ hs_a, float* __restrict__ hs_b)
{
    const int blk = blockIdx.x;
    const int b = blk >> 1;
    const int which = blk & 1;
    const float* xp  = which ? xpb   : xpa;
    const float* Whh = which ? Whh_b : Whh_a;
    const float* bhh = which ? bhh_b : bhh_a;
    float* hs        = which ? hs_b  : hs_a;

    const int t = threadIdx.x;       // 0..191
    const int g = t >> 6;            // gate: 0=r, 1=z, 2=n
    const int j = t & 63;

    __shared__ float gh_s[2][GG];

    // 64 weights of row g*64+j. volatile -> loads execute exactly once and
    // results cannot be recomputed; they must stay register-resident.
    float4 w[16];
    {
        const volatile float4* wrow =
            (const volatile float4*)&Whh[(size_t)(g * 64 + j) * HH];
        #pragma unroll
        for (int k = 0; k < 16; ++k) {
            float4 v;
            v.x = wrow[k].x; v.y = wrow[k].y; v.z = wrow[k].z; v.w = wrow[k].w;
            asm volatile("" : "+v"(v.x), "+v"(v.y), "+v"(v.z), "+v"(v.w));
            w[k] = v;
        }
    }
    const float bh = bhh[g * 64 + j];

    const float* xrow = xp + (size_t)b * SS * GG;
    float* hrow = hs + (size_t)b * SS * HH;
    float hcur = 0.f;

    float xg = xrow[g * 64 + j];
    float xn = xrow[128 + j];

#define RL(v, k) __int_as_float(__builtin_amdgcn_readlane(__float_as_int(v), (k)))

    for (int s = 0; s < SS; ++s) {
        const float* nx = xrow + GG;
        float nxg = nx[g * 64 + j];
        float nxn = nx[128 + j];

        float a0 = bh, a1 = 0.f, a2 = 0.f, a3 = 0.f;
        #pragma unroll
        for (int k = 0; k < 16; ++k) {
            float4 wk = w[k];
            float h0 = RL(hcur, 4*k + 0);
            float h1 = RL(hcur, 4*k + 1);
            float h2 = RL(hcur, 4*k + 2);
            float h3 = RL(hcur, 4*k + 3);
            a0 = fmaf(wk.x, h0, a0);
            a1 = fmaf(wk.y, h1, a1);
            a2 = fmaf(wk.z, h2, a2);
            a3 = fmaf(wk.w, h3, a3);
        }
        float pre = (a0 + a1) + (a2 + a3);
        gh_s[s & 1][t] = (g < 2) ? (xg + pre) : pre;

        // LDS-only barrier: don't drain vmcnt (prefetch stays in flight).
        asm volatile("s_waitcnt lgkmcnt(0)" ::: "memory");
        __builtin_amdgcn_s_barrier();
        asm volatile("" ::: "memory");

        float ghr = gh_s[s & 1][j];
        float ghz = gh_s[s & 1][64 + j];
        float ghn = gh_s[s & 1][128 + j];
        float r = sigmoid_f(ghr);
        float z = sigmoid_f(ghz);
        float n = tanh_f(xn + r * ghn);
        hcur = fmaf(z, hcur - n, n);
        if (g == 0) hrow[j] = hcur;

        xg = nxg; xn = nxn;
        xrow += GG;
        hrow += HH;
    }
#undef RL
}

// ---------------------------------------------------------------------------
// Per (b,j): wj = exp(h_alpha . Wa + ba) * M;  val[e] = tanh(h_beta . Wb[e] + bb[e]) * emb[e] * wj
// ---------------------------------------------------------------------------
__global__ __launch_bounds__(128) void attn_val_kernel(
    const float* __restrict__ h_alpha, const float* __restrict__ h_beta,
    const float* __restrict__ emb, const float* __restrict__ M,
    const float* __restrict__ Wa, const float* __restrict__ ba,
    const float* __restrict__ Wb, const float* __restrict__ bb,
    float* __restrict__ val, float* __restrict__ wj)
{
    const int bj = blockIdx.x;
    const int t = threadIdx.x;
    __shared__ float hb_s[HH];
    __shared__ float wj_s;

    if (t < 64) {
        hb_s[t] = h_beta[(size_t)bj * HH + t];
        float p = h_alpha[(size_t)bj * HH + t] * Wa[t];
        #pragma unroll
        for (int off = 32; off > 0; off >>= 1) p += __shfl_down(p, off);
        if (t == 0) {
            float a = __expf(p + ba[0]) * M[bj];
            wj_s = a;
            wj[bj] = a;
        }
    }
    __syncthreads();

    float acc = bb[t];
    const float4* wrow = (const float4*)&Wb[(size_t)t * HH];
    #pragma unroll
    for (int k = 0; k < 16; ++k) {
        float4 w4 = wrow[k];
        float4 h4 = *(const float4*)&hb_s[k * 4];
        acc += w4.x*h4.x + w4.y*h4.y + w4.z*h4.z + w4.w*h4.w;
    }
    float bw = tanh_f(acc);
    val[(size_t)bj * EE + t] = bw * emb[(size_t)bj * EE + t] * wj_s;
}

// ---------------------------------------------------------------------------
// Suffix scan, parallelized (r9). Old scan_kernel was 16 blocks x 256
// SEQUENTIAL iterations (~35us, latency-bound). Two-level version:
// scanA: grid (B,16): tile sums over 16 rows (fully parallel).
// scanB: grid (B,16): beyond-tile suffix (<=15 parallel loads) + 16-step
//        in-register suffix within the tile. ~5us total.
// ---------------------------------------------------------------------------
__global__ __launch_bounds__(128) void scanA_kernel(
    const float* __restrict__ val, const float* __restrict__ wj,
    float* __restrict__ tsum, float* __restrict__ wsum)
{
    const int b = blockIdx.x, tt = blockIdx.y;
    const int e = threadIdx.x;
    const int j0 = tt * 16;
    float s = 0.f;
    #pragma unroll
    for (int jj = 0; jj < 16; ++jj)
        s += val[((size_t)(b * SS + j0 + jj)) * EE + e];
    tsum[((size_t)(b * TT + tt)) * EE + e] = s;

    if (e < 16) {
        float p = wj[b * SS + j0 + e];
        #pragma unroll
        for (int off = 8; off > 0; off >>= 1) p += __shfl_down(p, off, 16);
        if (e == 0) wsum[b * TT + tt] = p;
    }
}

__global__ __launch_bounds__(128) void scanB_kernel(
    const float* __restrict__ val, const float* __restrict__ wj,
    const float* __restrict__ tsum, const float* __restrict__ wsum,
    float* __restrict__ wtd)
{
    const int b = blockIdx.x, tt = blockIdx.y;
    const int e = threadIdx.x;
    const int j0 = tt * 16;

    float se = 0.f;
    for (int t2 = tt + 1; t2 < TT; ++t2)
        se += tsum[((size_t)(b * TT + t2)) * EE + e];
    float d = 1e-10f;
    for (int t2 = tt + 1; t2 < TT; ++t2)
        d += wsum[b * TT + t2];

    for (int jj = 15; jj >= 0; --jj) {
        size_t idx = ((size_t)(b * SS + j0 + jj)) * EE + e;
        se += val[idx];
        d += wj[b * SS + j0 + jj];
        wtd[idx] = se / d;
    }
}

// ---------------------------------------------------------------------------
// all_output[b,s,l] = (weighted[b,s,:] . Wp[l,:] + bp[l]) * M[b,s]
// ---------------------------------------------------------------------------
__global__ __launch_bounds__(256) void proj_kernel(
    const float* __restrict__ wtd, const float* __restrict__ Wp,
    const float* __restrict__ bp, const float* __restrict__ M,
    float* __restrict__ out)
{
    __shared__ float wt_s[32][132];
    __shared__ float wp_s[8][132];
    const int t = threadIdx.x;
    const int row0 = blockIdx.x * 32;

    {
        int r = t >> 3;
        int q = t & 7;
        const float* src = &wtd[(size_t)(row0 + r) * EE];
        #pragma unroll
        for (int it = 0; it < 4; ++it) {
            int kk = (q + it * 8) * 4;
            *(float4*)&wt_s[r][kk] = *(const float4*)&src[kk];
        }
    }
    {
        int r = t >> 5;
        int q = t & 31;
        *(float4*)&wp_s[r][q * 4] = *(const float4*)&Wp[(size_t)r * EE + q * 4];
    }
    __syncthreads();

    const int r = t >> 3, l = t & 7;
    float acc = 0.f;
    #pragma unroll
    for (int i = 0; i < 32; ++i) {
        float4 a = *(const float4*)&wt_s[r][i * 4];
        float4 w = *(const float4*)&wp_s[l][i * 4];
        acc += a.x*w.x + a.y*w.y + a.z*w.z + a.w*w.w;
    }
    const int row = row0 + r;
    out[(size_t)row * LL + l] = (acc + bp[l]) * M[row];
}

// ---------------------------------------------------------------------------
// cur_output[b,l] = sum_s all_output[b,s,l] * cur_M[b,s]
// ---------------------------------------------------------------------------
__global__ __launch_bounds__(256) void cur_kernel(
    const float* __restrict__ out_all, const float* __restrict__ curM,
    float* __restrict__ out_cur)
{
    const int b = blockIdx.x;
    const int t = threadIdx.x;
    const int l = t & 7, c = t >> 3;
    float p = 0.f;
    #pragma unroll
    for (int k = 0; k < 8; ++k) {
        int s = c + k * 32;
        p += out_all[((size_t)(b * SS + s)) * LL + l] * curM[b * SS + s];
    }
    __shared__ float red[32][9];
    red[c][l] = p;
    __syncthreads();
    if (t < 8) {
        float sum = 0.f;
        for (int c2 = 0; c2 < 32; ++c2) sum += red[c2][t];
        out_cur[b * LL + t] = sum;
    }
}

// ---------------------------------------------------------------------------
extern "C" void kernel_launch(void* const* d_in, const int* in_sizes, int n_in,
                              void* d_out, int out_size, void* d_ws, size_t ws_size,
                              hipStream_t stream)
{
    const float* X       = (const float*)d_in[0];
    const float* M       = (const float*)d_in[1];
    const float* cur_M   = (const float*)d_in[2];
    const float* W_embed = (const float*)d_in[3];
    const float* b_embed = (const float*)d_in[4];
    const float* Wih_a   = (const float*)d_in[5];
    const float* Whh_a   = (const float*)d_in[6];
    const float* bih_a   = (const float*)d_in[7];
    const float* bhh_a   = (const float*)d_in[8];
    const float* Wih_b   = (const float*)d_in[9];
    const float* Whh_b   = (const float*)d_in[10];
    const float* bih_b   = (const float*)d_in[11];
    const float* bhh_b   = (const float*)d_in[12];
    const float* Wb      = (const float*)d_in[13];
    const float* bb      = (const float*)d_in[14];
    const float* Wa      = (const float*)d_in[15];
    const float* ba      = (const float*)d_in[16];
    const float* Wp      = (const float*)d_in[17];
    const float* bp      = (const float*)d_in[18];
    float* out = (float*)d_out;

    float* ws  = (float*)d_ws;
    float* emb = ws;                          // B*S*E
    float* xpa = emb + (size_t)BB*SS*EE;      // B*S*192
    float* xpb = xpa + (size_t)BB*SS*GG;
    float* ha  = xpb + (size_t)BB*SS*GG;      // B*S*H
    float* hb  = ha  + (size_t)BB*SS*HH;
    float* val = hb  + (size_t)BB*SS*HH;      // B*S*E
    float* wjv = val + (size_t)BB*SS*EE;      // B*S
    float* wtd = wjv + (size_t)BB*SS;         // B*S*E
    float* tsum = wtd + (size_t)BB*SS*EE;     // B*TT*E = 32768
    float* wsum = tsum + (size_t)BB*TT*EE;    // B*TT   = 256

    const int ROWS = BB * SS;                 // 4096

    gemm_bt<<<dim3(ROWS/32, EE/64), 256, 0, stream>>>(X, W_embed, b_embed, emb, EE, FF);
    gemm_bt_dual<<<dim3(ROWS/32, (GG+63)/64, 2), 256, 0, stream>>>(
        emb, Wih_a, bih_a, xpa, Wih_b, bih_b, xpb, GG, EE);
    gru_kernel<<<32, 192, 0, stream>>>(xpa, xpb, Whh_a, bhh_a, Whh_b, bhh_b, ha, hb);
    attn_val_kernel<<<ROWS, 128, 0, stream>>>(ha, hb, emb, M, Wa, ba, Wb, bb, val, wjv);
    scanA_kernel<<<dim3(BB, TT), 128, 0, stream>>>(val, wjv, tsum, wsum);
    scanB_kernel<<<dim3(BB, TT), 128, 0, stream>>>(val, wjv, tsum, wsum, wtd);
    proj_kernel<<<ROWS/32, 256, 0, stream>>>(wtd, Wp, bp, M, out);
    cur_kernel<<<BB, 256, 0, stream>>>(out, cur_M, out + (size_t)BB*SS*LL);
}

// Round 10
// 175.124 us; speedup vs baseline: 1.7177x; 1.0770x over previous
//
#include <hip/hip_runtime.h>
#include <math.h>

#define BB 16
#define SS 256
#define FF 512
#define EE 128
#define HH 64
#define GG 192  // 3H
#define LL 8
#define TT 16   // scan tile count (SS/16)

__device__ __forceinline__ float sigmoid_f(float x) {
    return 1.0f / (1.0f + __expf(-x));
}
__device__ __forceinline__ float tanh_f(float x) {
    return 1.0f - 2.0f / (1.0f + __expf(2.0f * x));
}

// ---------------------------------------------------------------------------
// Generic C[m,n] = sum_k A[m,k] * Bm[n,k] + bias[n]
// ---------------------------------------------------------------------------
__device__ __forceinline__ void gemm_bt_body(
    const float* __restrict__ A, const float* __restrict__ Bm,
    const float* __restrict__ bias, float* __restrict__ C,
    int N, int K)
{
    __shared__ float As[32][68];
    __shared__ float Bs[64][68];
    const int t = threadIdx.x;
    const int row0 = blockIdx.x * 32;
    const int col0 = blockIdx.y * 64;
    const int tr = t & 7;
    const int tc = t >> 3;
    float acc[4][2] = {{0.f,0.f},{0.f,0.f},{0.f,0.f},{0.f,0.f}};

    for (int k0 = 0; k0 < K; k0 += 64) {
        {
            int r = t >> 3;
            int q = t & 7;
            const float* src = &A[(size_t)(row0 + r) * K + k0];
            #pragma unroll
            for (int it = 0; it < 2; ++it) {
                int kk = (q + it * 8) * 4;
                *(float4*)&As[r][kk] = *(const float4*)&src[kk];
            }
        }
        {
            int r = t >> 2;
            int q = t & 3;
            int n = col0 + r;
            #pragma unroll
            for (int it = 0; it < 4; ++it) {
                int kk = (q + it * 4) * 4;
                float4 v = {0.f, 0.f, 0.f, 0.f};
                if (n < N) v = *(const float4*)&Bm[(size_t)n * K + k0 + kk];
                *(float4*)&Bs[r][kk] = v;
            }
        }
        __syncthreads();
        #pragma unroll
        for (int k = 0; k < 64; k += 4) {
            float4 av[4], bv[2];
            #pragma unroll
            for (int i = 0; i < 4; ++i) av[i] = *(const float4*)&As[tr + 8*i][k];
            #pragma unroll
            for (int j = 0; j < 2; ++j) bv[j] = *(const float4*)&Bs[tc + 32*j][k];
            #pragma unroll
            for (int i = 0; i < 4; ++i)
                #pragma unroll
                for (int j = 0; j < 2; ++j)
                    acc[i][j] += av[i].x*bv[j].x + av[i].y*bv[j].y
                               + av[i].z*bv[j].z + av[i].w*bv[j].w;
        }
        __syncthreads();
    }

    #pragma unroll
    for (int i = 0; i < 4; ++i) {
        int r = row0 + tr + 8*i;
        #pragma unroll
        for (int j = 0; j < 2; ++j) {
            int c = col0 + tc + 32*j;
            if (c < N) C[(size_t)r * N + c] = acc[i][j] + bias[c];
        }
    }
}

__global__ __launch_bounds__(256) void gemm_bt(
    const float* __restrict__ A, const float* __restrict__ Bm,
    const float* __restrict__ bias, float* __restrict__ C,
    int N, int K)
{
    gemm_bt_body(A, Bm, bias, C, N, K);
}

__global__ __launch_bounds__(256) void gemm_bt_dual(
    const float* __restrict__ A,
    const float* __restrict__ B0, const float* __restrict__ bias0, float* __restrict__ C0,
    const float* __restrict__ B1, const float* __restrict__ bias1, float* __restrict__ C1,
    int N, int K)
{
    const float* Bm   = blockIdx.z ? B1    : B0;
    const float* bias = blockIdx.z ? bias1 : bias0;
    float*       C    = blockIdx.z ? C1    : C0;
    gemm_bt_body(A, Bm, bias, C, N, K);
}

// ---------------------------------------------------------------------------
// GRU scan (r10). r7 3-wave structure (one gate per wave, lgkm-only barrier,
// double-buffered gh). Weight storage finally rule-#20-clean: SIXTEEN NAMED
// float4 locals — no arrays, no asm pins, no volatile. Post-mortem of r5-r9:
// every `float4 w[16]`-array variant sat at VGPR_Count 40-44 because the
// alloca was never SROA-promoted (asm/volatile on array elements blocks it);
// the array lived in scratch and each step re-read 256B/lane from scratch
// (~400 stall cyc). Named scalars are pure SSA: promotion is unconditional,
// 4-wide tuples don't fragment the allocator (r2-r4's f32x16 16-wide tuples
// did). Demand ~95 VGPR < 512 budget (launch_bounds min-waves=1).
// ---------------------------------------------------------------------------
__global__ __launch_bounds__(192, 1)
__attribute__((amdgpu_waves_per_eu(1, 1)))
void gru_kernel(
    const float* __restrict__ xpa, const float* __restrict__ xpb,
    const float* __restrict__ Whh_a, const float* __restrict__ bhh_a,
    const float* __restrict__ Whh_b, const float* __restrict__ bhh_b,
    float* __restrict__ hs_a, float* __restrict__ hs_b)
{
    const int blk = blockIdx.x;
    const int b = blk >> 1;
    const int which = blk & 1;
    const float* xp  = which ? xpb   : xpa;
    const float* Whh = which ? Whh_b : Whh_a;
    const float* bhh = which ? bhh_b : bhh_a;
    float* hs        = which ? hs_b  : hs_a;

    const int t = threadIdx.x;       // 0..191
    const int g = t >> 6;            // gate: 0=r, 1=z, 2=n
    const int j = t & 63;

    __shared__ float gh_s[2][GG];

    // 64 weights of row g*64+j as 16 NAMED float4 SSA values.
    const float4* wrow = (const float4*)&Whh[(size_t)(g * 64 + j) * HH];
    float4 w0  = wrow[0],  w1  = wrow[1],  w2  = wrow[2],  w3  = wrow[3];
    float4 w4  = wrow[4],  w5  = wrow[5],  w6  = wrow[6],  w7  = wrow[7];
    float4 w8  = wrow[8],  w9  = wrow[9],  w10 = wrow[10], w11 = wrow[11];
    float4 w12 = wrow[12], w13 = wrow[13], w14 = wrow[14], w15 = wrow[15];

    const float bh = bhh[g * 64 + j];

    const float* xrow = xp + (size_t)b * SS * GG;
    float* hrow = hs + (size_t)b * SS * HH;
    float hcur = 0.f;

    float xg = xrow[g * 64 + j];
    float xn = xrow[128 + j];

#define RL(v, k) __int_as_float(__builtin_amdgcn_readlane(__float_as_int(v), (k)))
#define DOT4(W, i)                                  \
    a0 = fmaf(W.x, RL(hcur, 4*(i) + 0), a0);        \
    a1 = fmaf(W.y, RL(hcur, 4*(i) + 1), a1);        \
    a2 = fmaf(W.z, RL(hcur, 4*(i) + 2), a2);        \
    a3 = fmaf(W.w, RL(hcur, 4*(i) + 3), a3);

    for (int s = 0; s < SS; ++s) {
        // Prefetch next step's xp (stays in flight across the lgkm-only
        // barrier; last iter reads past the array into adjacent workspace —
        // harmless, value discarded).
        const float* nx = xrow + GG;
        float nxg = nx[g * 64 + j];
        float nxn = nx[128 + j];

        float a0 = bh, a1 = 0.f, a2 = 0.f, a3 = 0.f;
        DOT4(w0, 0)   DOT4(w1, 1)   DOT4(w2, 2)   DOT4(w3, 3)
        DOT4(w4, 4)   DOT4(w5, 5)   DOT4(w6, 6)   DOT4(w7, 7)
        DOT4(w8, 8)   DOT4(w9, 9)   DOT4(w10, 10) DOT4(w11, 11)
        DOT4(w12, 12) DOT4(w13, 13) DOT4(w14, 14) DOT4(w15, 15)
        float pre = (a0 + a1) + (a2 + a3);
        gh_s[s & 1][t] = (g < 2) ? (xg + pre) : pre;

        // LDS-only barrier: don't drain vmcnt.
        asm volatile("s_waitcnt lgkmcnt(0)" ::: "memory");
        __builtin_amdgcn_s_barrier();
        asm volatile("" ::: "memory");

        float ghr = gh_s[s & 1][j];
        float ghz = gh_s[s & 1][64 + j];
        float ghn = gh_s[s & 1][128 + j];
        float r = sigmoid_f(ghr);
        float z = sigmoid_f(ghz);
        float n = tanh_f(xn + r * ghn);
        hcur = fmaf(z, hcur - n, n);
        if (g == 0) hrow[j] = hcur;

        xg = nxg; xn = nxn;
        xrow += GG;
        hrow += HH;
    }
#undef DOT4
#undef RL
}

// ---------------------------------------------------------------------------
// Per (b,j): wj = exp(h_alpha . Wa + ba) * M;  val[e] = tanh(h_beta . Wb[e] + bb[e]) * emb[e] * wj
// ---------------------------------------------------------------------------
__global__ __launch_bounds__(128) void attn_val_kernel(
    const float* __restrict__ h_alpha, const float* __restrict__ h_beta,
    const float* __restrict__ emb, const float* __restrict__ M,
    const float* __restrict__ Wa, const float* __restrict__ ba,
    const float* __restrict__ Wb, const float* __restrict__ bb,
    float* __restrict__ val, float* __restrict__ wj)
{
    const int bj = blockIdx.x;
    const int t = threadIdx.x;
    __shared__ float hb_s[HH];
    __shared__ float wj_s;

    if (t < 64) {
        hb_s[t] = h_beta[(size_t)bj * HH + t];
        float p = h_alpha[(size_t)bj * HH + t] * Wa[t];
        #pragma unroll
        for (int off = 32; off > 0; off >>= 1) p += __shfl_down(p, off);
        if (t == 0) {
            float a = __expf(p + ba[0]) * M[bj];
            wj_s = a;
            wj[bj] = a;
        }
    }
    __syncthreads();

    float acc = bb[t];
    const float4* wrow = (const float4*)&Wb[(size_t)t * HH];
    #pragma unroll
    for (int k = 0; k < 16; ++k) {
        float4 w4 = wrow[k];
        float4 h4 = *(const float4*)&hb_s[k * 4];
        acc += w4.x*h4.x + w4.y*h4.y + w4.z*h4.z + w4.w*h4.w;
    }
    float bw = tanh_f(acc);
    val[(size_t)bj * EE + t] = bw * emb[(size_t)bj * EE + t] * wj_s;
}

// ---------------------------------------------------------------------------
// Suffix scan, two-level parallel (r9): scanA tile sums, scanB suffix.
// ---------------------------------------------------------------------------
__global__ __launch_bounds__(128) void scanA_kernel(
    const float* __restrict__ val, const float* __restrict__ wj,
    float* __restrict__ tsum, float* __restrict__ wsum)
{
    const int b = blockIdx.x, tt = blockIdx.y;
    const int e = threadIdx.x;
    const int j0 = tt * 16;
    float s = 0.f;
    #pragma unroll
    for (int jj = 0; jj < 16; ++jj)
        s += val[((size_t)(b * SS + j0 + jj)) * EE + e];
    tsum[((size_t)(b * TT + tt)) * EE + e] = s;

    if (e < 16) {
        float p = wj[b * SS + j0 + e];
        #pragma unroll
        for (int off = 8; off > 0; off >>= 1) p += __shfl_down(p, off, 16);
        if (e == 0) wsum[b * TT + tt] = p;
    }
}

__global__ __launch_bounds__(128) void scanB_kernel(
    const float* __restrict__ val, const float* __restrict__ wj,
    const float* __restrict__ tsum, const float* __restrict__ wsum,
    float* __restrict__ wtd)
{
    const int b = blockIdx.x, tt = blockIdx.y;
    const int e = threadIdx.x;
    const int j0 = tt * 16;

    float se = 0.f;
    for (int t2 = tt + 1; t2 < TT; ++t2)
        se += tsum[((size_t)(b * TT + t2)) * EE + e];
    float d = 1e-10f;
    for (int t2 = tt + 1; t2 < TT; ++t2)
        d += wsum[b * TT + t2];

    for (int jj = 15; jj >= 0; --jj) {
        size_t idx = ((size_t)(b * SS + j0 + jj)) * EE + e;
        se += val[idx];
        d += wj[b * SS + j0 + jj];
        wtd[idx] = se / d;
    }
}

// ---------------------------------------------------------------------------
// all_output[b,s,l] = (weighted[b,s,:] . Wp[l,:] + bp[l]) * M[b,s]
// ---------------------------------------------------------------------------
__global__ __launch_bounds__(256) void proj_kernel(
    const float* __restrict__ wtd, const float* __restrict__ Wp,
    const float* __restrict__ bp, const float* __restrict__ M,
    float* __restrict__ out)
{
    __shared__ float wt_s[32][132];
    __shared__ float wp_s[8][132];
    const int t = threadIdx.x;
    const int row0 = blockIdx.x * 32;

    {
        int r = t >> 3;
        int q = t & 7;
        const float* src = &wtd[(size_t)(row0 + r) * EE];
        #pragma unroll
        for (int it = 0; it < 4; ++it) {
            int kk = (q + it * 8) * 4;
            *(float4*)&wt_s[r][kk] = *(const float4*)&src[kk];
        }
    }
    {
        int r = t >> 5;
        int q = t & 31;
        *(float4*)&wp_s[r][q * 4] = *(const float4*)&Wp[(size_t)r * EE + q * 4];
    }
    __syncthreads();

    const int r = t >> 3, l = t & 7;
    float acc = 0.f;
    #pragma unroll
    for (int i = 0; i < 32; ++i) {
        float4 a = *(const float4*)&wt_s[r][i * 4];
        float4 w = *(const float4*)&wp_s[l][i * 4];
        acc += a.x*w.x + a.y*w.y + a.z*w.z + a.w*w.w;
    }
    const int row = row0 + r;
    out[(size_t)row * LL + l] = (acc + bp[l]) * M[row];
}

// ---------------------------------------------------------------------------
// cur_output[b,l] = sum_s all_output[b,s,l] * cur_M[b,s]
// ---------------------------------------------------------------------------
__global__ __launch_bounds__(256) void cur_kernel(
    const float* __restrict__ out_all, const float* __restrict__ curM,
    float* __restrict__ out_cur)
{
    const int b = blockIdx.x;
    const int t = threadIdx.x;
    const int l = t & 7, c = t >> 3;
    float p = 0.f;
    #pragma unroll
    for (int k = 0; k < 8; ++k) {
        int s = c + k * 32;
        p += out_all[((size_t)(b * SS + s)) * LL + l] * curM[b * SS + s];
    }
    __shared__ float red[32][9];
    red[c][l] = p;
    __syncthreads();
    if (t < 8) {
        float sum = 0.f;
        for (int c2 = 0; c2 < 32; ++c2) sum += red[c2][t];
        out_cur[b * LL + t] = sum;
    }
}

// ---------------------------------------------------------------------------
extern "C" void kernel_launch(void* const* d_in, const int* in_sizes, int n_in,
                              void* d_out, int out_size, void* d_ws, size_t ws_size,
                              hipStream_t stream)
{
    const float* X       = (const float*)d_in[0];
    const float* M       = (const float*)d_in[1];
    const float* cur_M   = (const float*)d_in[2];
    const float* W_embed = (const float*)d_in[3];
    const float* b_embed = (const float*)d_in[4];
    const float* Wih_a   = (const float*)d_in[5];
    const float* Whh_a   = (const float*)d_in[6];
    const float* bih_a   = (const float*)d_in[7];
    const float* bhh_a   = (const float*)d_in[8];
    const float* Wih_b   = (const float*)d_in[9];
    const float* Whh_b   = (const float*)d_in[10];
    const float* bih_b   = (const float*)d_in[11];
    const float* bhh_b   = (const float*)d_in[12];
    const float* Wb      = (const float*)d_in[13];
    const float* bb      = (const float*)d_in[14];
    const float* Wa      = (const float*)d_in[15];
    const float* ba      = (const float*)d_in[16];
    const float* Wp      = (const float*)d_in[17];
    const float* bp      = (const float*)d_in[18];
    float* out = (float*)d_out;

    float* ws  = (float*)d_ws;
    float* emb = ws;                          // B*S*E
    float* xpa = emb + (size_t)BB*SS*EE;      // B*S*192
    float* xpb = xpa + (size_t)BB*SS*GG;
    float* ha  = xpb + (size_t)BB*SS*GG;      // B*S*H
    float* hb  = ha  + (size_t)BB*SS*HH;
    float* val = hb  + (size_t)BB*SS*HH;      // B*S*E
    float* wjv = val + (size_t)BB*SS*EE;      // B*S
    float* wtd = wjv + (size_t)BB*SS;         // B*S*E
    float* tsum = wtd + (size_t)BB*SS*EE;     // B*TT*E
    float* wsum = tsum + (size_t)BB*TT*EE;    // B*TT

    const int ROWS = BB * SS;                 // 4096

    gemm_bt<<<dim3(ROWS/32, EE/64), 256, 0, stream>>>(X, W_embed, b_embed, emb, EE, FF);
    gemm_bt_dual<<<dim3(ROWS/32, (GG+63)/64, 2), 256, 0, stream>>>(
        emb, Wih_a, bih_a, xpa, Wih_b, bih_b, xpb, GG, EE);
    gru_kernel<<<32, 192, 0, stream>>>(xpa, xpb, Whh_a, bhh_a, Whh_b, bhh_b, ha, hb);
    attn_val_kernel<<<ROWS, 128, 0, stream>>>(ha, hb, emb, M, Wa, ba, Wb, bb, val, wjv);
    scanA_kernel<<<dim3(BB, TT), 128, 0, stream>>>(val, wjv, tsum, wsum);
    scanB_kernel<<<dim3(BB, TT), 128, 0, stream>>>(val, wjv, tsum, wsum, wtd);
    proj_kernel<<<ROWS/32, 256, 0, stream>>>(wtd, Wp, bp, M, out);
    cur_kernel<<<BB, 256, 0, stream>>>(out, cur_M, out + (size_t)BB*SS*LL);
}